// Round 6
// baseline (933.361 us; speedup 1.0000x reference)
//
#include <hip/hip_runtime.h>
#include <math.h>

#define BS 256
#define MM 128
#define NN 1024
#define ITERS 100
#define ALPHA 0.1f
#define AST 129
#define IST 129
#define TRP 132

typedef _Float16 half8 __attribute__((ext_vector_type(8)));
typedef _Float16 half4 __attribute__((ext_vector_type(4)));
typedef _Float16 half2v __attribute__((ext_vector_type(2)));
typedef float f32x4 __attribute__((ext_vector_type(4)));

// Exact butterfly add via DPP (VALU pipe, no LDS). Controls:
//   0xB1 quad_perm xor1 | 0x4E quad_perm xor2 | 0x141 row_half_mirror (xor7
//   within 8) | 0x128 row_ror:8 (xor8 within 16-lane row)
template <int CTRL>
__device__ __forceinline__ float dpp_add(float x) {
  int xi = __builtin_bit_cast(int, x);
  int r = __builtin_amdgcn_update_dpp(xi, xi, CTRL, 0xf, 0xf, true);
  return x + __builtin_bit_cast(float, r);
}

// ---------------------------------------------------------------------------
// AAT: 2 blocks per batch (row-halves p=0/1), 512 threads = 8 waves,
// 2 blocks/CU so barrier stalls of one block hide under the other.
// Split-fp16 MFMA (hi/lo). Each block stages the FULL 128-row k-slice
// (needed for B-operands), computes C rows [64p,64p+64), and emits its
// half of the fp16 AT k-slices (identical conversion path as before).
__global__ __attribute__((amdgpu_waves_per_eu(4, 4)))
__launch_bounds__(512) void k_aat(const float* __restrict__ A,
                                  float* __restrict__ G,
                                  _Float16* __restrict__ ATh) {
  __shared__ float As[64 * AST];                          // 33,024
  __shared__ __align__(16) _Float16 Thi[8][2][64][8];     // 16,384
  __shared__ __align__(16) _Float16 Tlo[8][2][64][8];     // 16,384
  int b = blockIdx.x >> 1;
  int p = blockIdx.x & 1;          // row-half
  int tid = threadIdx.x;
  const float* Ab = A + (size_t)b * MM * NN;
  float* Cb = G + (size_t)b * MM * MM;
  _Float16* ATb = ATh + (size_t)b * NN * MM;

  int lane = tid & 63;
  int w = tid >> 6;      // wave 0..7
  int wr = w & 1;        // row strips {4p+2wr, 4p+2wr+1}
  int wc = w >> 1;       // col strips {2wc, 2wc+1}

  f32x4 acc[2][2];
#pragma unroll
  for (int i = 0; i < 2; ++i)
#pragma unroll
    for (int jj = 0; jj < 2; ++jj) acc[i][jj] = (f32x4){0.f, 0.f, 0.f, 0.f};

  // staging geometry (4 chunks/thread)
  float4 va[4];
#pragma unroll
  for (int s = 0; s < 4; ++s) {
    int c = tid + s * 512;
    int m = c >> 4;
    int kl = (c & 15) * 4;
    va[s] = *(const float4*)&Ab[(size_t)m * NN + kl];
  }

  for (int t = 0; t < 16; ++t) {
    int k0 = t * 64;
#pragma unroll
    for (int s = 0; s < 4; ++s) {
      int c = tid + s * 512;
      int m = c >> 4;
      int kl = (c & 15) * 4;
      float4 v = va[s];
      As[(kl + 0) * AST + m] = v.x;
      As[(kl + 1) * AST + m] = v.y;
      As[(kl + 2) * AST + m] = v.z;
      As[(kl + 3) * AST + m] = v.w;
      _Float16 h0 = (_Float16)v.x, h1 = (_Float16)v.y;
      _Float16 h2 = (_Float16)v.z, h3 = (_Float16)v.w;
      half4 hv = {h0, h1, h2, h3};
      half4 lv = {(_Float16)(v.x - (float)h0), (_Float16)(v.y - (float)h1),
                  (_Float16)(v.z - (float)h2), (_Float16)(v.w - (float)h3)};
      int strip = m >> 4;
      int kc = kl >> 5;
      int ln = (m & 15) + (((kl & 31) >> 3) << 4);
      int j0 = kl & 7;
      *(half4*)&Thi[strip][kc][ln][j0] = hv;
      *(half4*)&Tlo[strip][kc][ln][j0] = lv;
    }
    __syncthreads();
    // prefetch next tile (latency hides under emit + MFMA)
    if (t < 15) {
#pragma unroll
      for (int s = 0; s < 4; ++s) {
        int c = tid + s * 512;
        int m = c >> 4;
        int kl = (c & 15) * 4;
        va[s] = *(const float4*)&Ab[(size_t)m * NN + k0 + 64 + kl];
      }
    }
    // emit this block's half of the fp16 AT k-slice
#pragma unroll
    for (int s = 0; s < 4; ++s) {
      int idx = tid + s * 512;        // 0..2047
      int nl = 32 * p + (idx >> 6);   // 32p..32p+31
      int mp = idx & 63;
      half2v hv;
      hv[0] = (_Float16)As[nl * AST + 2 * mp];
      hv[1] = (_Float16)As[nl * AST + 2 * mp + 1];
      *(half2v*)&ATb[(size_t)(k0 + nl) * MM + 2 * mp] = hv;
    }
#pragma unroll
    for (int kc = 0; kc < 2; ++kc) {
      half8 ahi[2], alo[2], bhi[2], blo[2];
#pragma unroll
      for (int i = 0; i < 2; ++i) {
        ahi[i] = *(const half8*)&Thi[4 * p + 2 * wr + i][kc][lane][0];
        alo[i] = *(const half8*)&Tlo[4 * p + 2 * wr + i][kc][lane][0];
        bhi[i] = *(const half8*)&Thi[2 * wc + i][kc][lane][0];
        blo[i] = *(const half8*)&Tlo[2 * wc + i][kc][lane][0];
      }
#pragma unroll
      for (int i = 0; i < 2; ++i)
#pragma unroll
        for (int jj = 0; jj < 2; ++jj) {
          acc[i][jj] = __builtin_amdgcn_mfma_f32_16x16x32_f16(
              ahi[i], bhi[jj], acc[i][jj], 0, 0, 0);
          acc[i][jj] = __builtin_amdgcn_mfma_f32_16x16x32_f16(
              ahi[i], blo[jj], acc[i][jj], 0, 0, 0);
          acc[i][jj] = __builtin_amdgcn_mfma_f32_16x16x32_f16(
              alo[i], bhi[jj], acc[i][jj], 0, 0, 0);
        }
    }
    __syncthreads();
  }
  // write C rows [64p,64p+64): D layout col=lane&15, row=4*(lane>>4)+r
  int rbase = 4 * (lane >> 4), cbase = lane & 15;
#pragma unroll
  for (int i = 0; i < 2; ++i)
#pragma unroll
    for (int jj = 0; jj < 2; ++jj) {
      int r0 = (4 * p + 2 * wr + i) * 16 + rbase;
      int c0 = (2 * wc + jj) * 16 + cbase;
#pragma unroll
      for (int r_ = 0; r_ < 4; ++r_)
        Cb[(size_t)(r0 + r_) * MM + c0] = acc[i][jj][r_];
    }
}

// ---------------------------------------------------------------------------
// INV: register-resident Gauss-Jordan (round-5 phase-2, proven). 1024 thr.
// Loads fp32 G from global into LDS, inverts in registers with 1KB ping-pong
// stashes (one barrier/step), exports fp16 Gh ALIASED ONTO ITS OWN G SLOT
// (G fully consumed before any Gh write -> race-free; keeps ws at 83.8 MB).
__global__ __attribute__((amdgpu_waves_per_eu(4, 4)))
__launch_bounds__(1024) void k_inv(float* __restrict__ G) {
  __shared__ float Msh[MM * IST];
  __shared__ float fcol[2][MM];
  __shared__ float frow[2][MM];
  int b = blockIdx.x;
  int tid = threadIdx.x;
  float* Gb = G + (size_t)b * MM * MM;
#pragma unroll
  for (int s = 0; s < 4; ++s) {
    int idx = (tid + s * 1024) * 4;
    float4 v = *(const float4*)&Gb[idx];
    int i = idx >> 7, j = idx & 127;
    Msh[i * IST + j + 0] = v.x;
    Msh[i * IST + j + 1] = v.y;
    Msh[i * IST + j + 2] = v.z;
    Msh[i * IST + j + 3] = v.w;
  }
  __syncthreads();
  int j = tid & 127;
  int i0 = (tid >> 7) * 16;
  float m[16];
#pragma unroll
  for (int ii = 0; ii < 16; ++ii) m[ii] = Msh[(i0 + ii) * IST + j];
  if (tid < MM) {
    fcol[0][tid] = Msh[tid * IST];   // col 0
    frow[0][tid] = Msh[tid];         // row 0
  }
  __syncthreads();
  int cur = 0;
  for (int kb = 0; kb < 8; ++kb) {
#pragma unroll
    for (int kq = 0; kq < 16; ++kq) {
      int k = kb * 16 + kq;
      float p = 1.0f / fcol[cur][k];
      float mkj = frow[cur][j];
      float fik[16];
#pragma unroll
      for (int q = 0; q < 4; ++q) {
        f32x4 fv = *(const f32x4*)&fcol[cur][i0 + 4 * q];
        fik[4 * q + 0] = fv[0]; fik[4 * q + 1] = fv[1];
        fik[4 * q + 2] = fv[2]; fik[4 * q + 3] = fv[3];
      }
      float pmkj = p * mkj;
      bool pivslab = (i0 == kb * 16);
      if (j == k) {
#pragma unroll
        for (int ii = 0; ii < 16; ++ii) m[ii] = -p * fik[ii];
        if (pivslab) m[kq] = p;
      } else {
#pragma unroll
        for (int ii = 0; ii < 16; ++ii) m[ii] = fmaf(-fik[ii], pmkj, m[ii]);
        if (pivslab) m[kq] = pmkj;
      }
      int nxt = cur ^ 1;
      if (k < MM - 1) {
        if (j == k + 1) {
#pragma unroll
          for (int ii = 0; ii < 16; ++ii) fcol[nxt][i0 + ii] = m[ii];
        }
        if (i0 == ((k + 1) & ~15)) frow[nxt][j] = m[(kq + 1) & 15];
      }
      __syncthreads();
      cur = nxt;
    }
  }
  // export G as fp16 row-major into this batch's own (consumed) G slot
  _Float16* Ghb = (_Float16*)Gb;
#pragma unroll
  for (int ii = 0; ii < 16; ++ii)
    Ghb[(size_t)(i0 + ii) * MM + j] = (_Float16)m[ii];
}

// ---------------------------------------------------------------------------
// MAIN: persistent solver (round-5 structure). This round: med3-clamp
// soft-threshold -- xc=clamp(z,-td,td); xh=(z-xc)*di -- bit-exact vs the
// branch form, ~90 fewer VALU instr/thread/iter.
__global__ __attribute__((amdgpu_waves_per_eu(4, 4)))
__launch_bounds__(1024) void k_main(
    const _Float16* __restrict__ AT, const float* __restrict__ G,
    const float* __restrict__ bvec, const float* __restrict__ D1,
    const float* __restrict__ D2, float* __restrict__ out) {
  __shared__ __align__(16) _Float16 AL[512 * MM];   // 131,072
  __shared__ float2 tdi_sh[NN];                     // 8,192
  __shared__ float b_sh[MM];
  __shared__ __align__(16) _Float16 s_h[MM];
  __shared__ __align__(16) _Float16 u_h[MM];
  __shared__ __align__(16) float t_redW[32][TRP];   // 16,896

  int b = blockIdx.x;
  int tid = threadIdx.x;
  const _Float16* ATb = AT + (size_t)b * NN * MM;
  const _Float16* Ghb = (const _Float16*)(G + (size_t)b * MM * MM);

  // ---- G fragment: 8 threads per row, 16 elems each, packed fp16 (8 VGPRs)
  int sub = tid & 7, rrow = tid >> 3;
  float ghf[8];
  {
    half8 g0 = *(const half8*)&Ghb[(size_t)rrow * MM + 16 * sub];
    half8 g1 = *(const half8*)&Ghb[(size_t)rrow * MM + 16 * sub + 8];
    f32x4 gA = __builtin_bit_cast(f32x4, g0);
    f32x4 gB = __builtin_bit_cast(f32x4, g1);
#pragma unroll
    for (int s = 0; s < 4; ++s) {
      ghf[s] = gA[s];
      ghf[4 + s] = gB[s];
    }
  }
#pragma unroll
  for (int s = 0; s < 8; ++s) asm volatile("" : "+v"(ghf[s]));
  {
    float d1 = D1[(size_t)b * NN + tid];
    float d2 = D2[(size_t)b * NN + tid];
    float2 td2;
    td2.x = ALPHA * fabsf(d1);
    td2.y = 1.0f / (1.0f + 2.0f * ALPHA * d2 * d2);
    tdi_sh[tid] = td2;
  }
  if (tid < MM) {
    float bb = bvec[(size_t)b * MM + tid];
    b_sh[tid] = bb;
    s_h[tid] = (_Float16)(-bb);   // s_0 = A*y_0 - b = -b
  }

  int l8 = tid & 7;            // lane in 8-group
  int g = (tid >> 3) & 7;      // group within wave (8 groups)
  int w = tid >> 6;            // wave 0..15
  int mb = 16 * l8;            // m-slice base (16 elems/lane)
  int alsw = (g & 1) * 8;      // AL parity swizzle

  // ---- LDS cols: AL col c holds n = 64*(c>>5)+32+(c&31); 16B parity swizzle
#pragma unroll
  for (int i = 0; i < 8; ++i) {
    int c = tid + 1024 * i;
    int col = c >> 4;
    int m8 = (c & 15) * 8;
    int n = 32 * (col >> 5) + 32 + col;
    int phys = m8 ^ ((col & 1) << 3);
    *(half8*)&AL[col * MM + phys] = *(const half8*)&ATb[(size_t)n * MM + m8];
  }

  // ---- register cols: n = 64w+16+g and 64w+24+g (16 VGPRs, pinned)
  float rcw[16];
  {
    int n0 = 64 * w + 16 + g, n1 = 64 * w + 24 + g;
    f32x4 v0 = *(const f32x4*)&ATb[(size_t)n0 * MM + mb];
    f32x4 v1 = *(const f32x4*)&ATb[(size_t)n0 * MM + mb + 8];
    f32x4 v2 = *(const f32x4*)&ATb[(size_t)n1 * MM + mb];
    f32x4 v3 = *(const f32x4*)&ATb[(size_t)n1 * MM + mb + 8];
    rcw[0] = v0[0]; rcw[1] = v0[1]; rcw[2] = v0[2]; rcw[3] = v0[3];
    rcw[4] = v1[0]; rcw[5] = v1[1]; rcw[6] = v1[2]; rcw[7] = v1[3];
    rcw[8] = v2[0]; rcw[9] = v2[1]; rcw[10] = v2[2]; rcw[11] = v2[3];
    rcw[12] = v3[0]; rcw[13] = v3[1]; rcw[14] = v3[2]; rcw[15] = v3[3];
  }
#pragma unroll
  for (int k = 0; k < 16; ++k) asm volatile("" : "+v"(rcw[k]));

  // ---- z state in registers: 8 cols/group, replicated across the 8 lanes
  float zz[8];
#pragma unroll
  for (int k = 0; k < 8; ++k) zz[k] = 0.0f;

  __syncthreads();

  for (int it = 0; it < ITERS; ++it) {
    bool last = (it == ITERS - 1);

    // ---- issue streamed-col loads early (n = 64w+g, 64w+8+g)
    f32x4 sa0 = *(const f32x4*)&ATb[(size_t)(64 * w + g) * MM + mb];
    f32x4 sa1 = *(const f32x4*)&ATb[(size_t)(64 * w + g) * MM + mb + 8];
    f32x4 sb0 = *(const f32x4*)&ATb[(size_t)(64 * w + 8 + g) * MM + mb];
    f32x4 sb1 = *(const f32x4*)&ATb[(size_t)(64 * w + 8 + g) * MM + mb + 8];

    // ---- u = G * s  (8 threads per row, packed fp16 dot; DPP 8-lane reduce)
    {
      int j0 = 16 * sub;
      half8 sA = *(const half8*)&s_h[j0];
      half8 sB = *(const half8*)&s_h[j0 + 8];
      float up = 0.0f;
      up = __builtin_amdgcn_fdot2(__builtin_bit_cast(half2v, ghf[0]),
                                  __builtin_shufflevector(sA, sA, 0, 1), up, false);
      up = __builtin_amdgcn_fdot2(__builtin_bit_cast(half2v, ghf[1]),
                                  __builtin_shufflevector(sA, sA, 2, 3), up, false);
      up = __builtin_amdgcn_fdot2(__builtin_bit_cast(half2v, ghf[2]),
                                  __builtin_shufflevector(sA, sA, 4, 5), up, false);
      up = __builtin_amdgcn_fdot2(__builtin_bit_cast(half2v, ghf[3]),
                                  __builtin_shufflevector(sA, sA, 6, 7), up, false);
      up = __builtin_amdgcn_fdot2(__builtin_bit_cast(half2v, ghf[4]),
                                  __builtin_shufflevector(sB, sB, 0, 1), up, false);
      up = __builtin_amdgcn_fdot2(__builtin_bit_cast(half2v, ghf[5]),
                                  __builtin_shufflevector(sB, sB, 2, 3), up, false);
      up = __builtin_amdgcn_fdot2(__builtin_bit_cast(half2v, ghf[6]),
                                  __builtin_shufflevector(sB, sB, 4, 5), up, false);
      up = __builtin_amdgcn_fdot2(__builtin_bit_cast(half2v, ghf[7]),
                                  __builtin_shufflevector(sB, sB, 6, 7), up, false);
      up = dpp_add<0xB1>(up);
      up = dpp_add<0x4E>(up);
      up = dpp_add<0x141>(up);
      if (sub == 0) u_h[rrow] = (_Float16)up;
    }
    __syncthreads();
    half8 uA = *(const half8*)&u_h[mb];
    half8 uB = *(const half8*)&u_h[mb + 8];
    half2v u0 = __builtin_shufflevector(uA, uA, 0, 1);
    half2v u1 = __builtin_shufflevector(uA, uA, 2, 3);
    half2v u2 = __builtin_shufflevector(uA, uA, 4, 5);
    half2v u3 = __builtin_shufflevector(uA, uA, 6, 7);
    half2v u4 = __builtin_shufflevector(uB, uB, 0, 1);
    half2v u5 = __builtin_shufflevector(uB, uB, 2, 3);
    half2v u6 = __builtin_shufflevector(uB, uB, 4, 5);
    half2v u7 = __builtin_shufflevector(uB, uB, 6, 7);

    float t[16];
#pragma unroll
    for (int k = 0; k < 16; ++k) t[k] = 0.0f;

    // z passed BY VALUE, new z returned (no address-taken state).
    auto colstep = [&](half8 ha, half8 hb, int n, float zv) -> float {
      float cp = 0.0f;
      cp = __builtin_amdgcn_fdot2(__builtin_shufflevector(ha, ha, 0, 1), u0, cp, false);
      cp = __builtin_amdgcn_fdot2(__builtin_shufflevector(ha, ha, 2, 3), u1, cp, false);
      cp = __builtin_amdgcn_fdot2(__builtin_shufflevector(ha, ha, 4, 5), u2, cp, false);
      cp = __builtin_amdgcn_fdot2(__builtin_shufflevector(ha, ha, 6, 7), u3, cp, false);
      cp = __builtin_amdgcn_fdot2(__builtin_shufflevector(hb, hb, 0, 1), u4, cp, false);
      cp = __builtin_amdgcn_fdot2(__builtin_shufflevector(hb, hb, 2, 3), u5, cp, false);
      cp = __builtin_amdgcn_fdot2(__builtin_shufflevector(hb, hb, 4, 5), u6, cp, false);
      cp = __builtin_amdgcn_fdot2(__builtin_shufflevector(hb, hb, 6, 7), u7, cp, false);
      cp = dpp_add<0xB1>(cp);    // xor1
      cp = dpp_add<0x4E>(cp);    // xor2
      cp = dpp_add<0x141>(cp);   // half_mirror: 8-sum in all 8 lanes
      float2 tdi = tdi_sh[n];
      float td = tdi.x, di = tdi.y;
      // med3 soft-threshold: clamp + sub + mul (bit-exact vs branch form)
      float xc = fminf(fmaxf(zv, -td), td);
      float xh = (zv - xc) * di;
      if (!last) {
        float z1 = xh - cp;                     // z_{i+1}
        float xc1 = fminf(fmaxf(z1, -td), td);
        float xh1 = (z1 - xc1) * di;
        float y = 2.0f * xh1 - z1;              // y_{i+1}
        f32x4 wa = __builtin_bit_cast(f32x4, ha);
        f32x4 wb = __builtin_bit_cast(f32x4, hb);
#pragma unroll
        for (int i2 = 0; i2 < 4; ++i2) {
          asm("v_fma_mix_f32 %0, %1, %2, %0 op_sel_hi:[1,0,0]"
              : "+v"(t[2 * i2]) : "v"(wa[i2]), "v"(y));
          asm("v_fma_mix_f32 %0, %1, %2, %0 op_sel:[1,0,0] op_sel_hi:[1,0,0]"
              : "+v"(t[2 * i2 + 1]) : "v"(wa[i2]), "v"(y));
          asm("v_fma_mix_f32 %0, %1, %2, %0 op_sel_hi:[1,0,0]"
              : "+v"(t[8 + 2 * i2]) : "v"(wb[i2]), "v"(y));
          asm("v_fma_mix_f32 %0, %1, %2, %0 op_sel:[1,0,0] op_sel_hi:[1,0,0]"
              : "+v"(t[8 + 2 * i2 + 1]) : "v"(wb[i2]), "v"(y));
        }
        return z1;
      } else {
        float y = 2.0f * xh - zv;               // y_99 from z_99
        if (l8 == 0) out[(size_t)b * NN + n] = y - cp;   // x_99 direct
        return zv;
      }
    };

    // register cols, then LDS cols, then streamed (loads have arrived)
    {
      f32x4 ra = {rcw[0], rcw[1], rcw[2], rcw[3]};
      f32x4 rb = {rcw[4], rcw[5], rcw[6], rcw[7]};
      zz[0] = colstep(__builtin_bit_cast(half8, ra),
                      __builtin_bit_cast(half8, rb), 64 * w + 16 + g, zz[0]);
      f32x4 rc_ = {rcw[8], rcw[9], rcw[10], rcw[11]};
      f32x4 rd_ = {rcw[12], rcw[13], rcw[14], rcw[15]};
      zz[1] = colstep(__builtin_bit_cast(half8, rc_),
                      __builtin_bit_cast(half8, rd_), 64 * w + 24 + g, zz[1]);
    }
#pragma unroll
    for (int j = 0; j < 4; ++j) {
      const _Float16* ap = &AL[(32 * w + 8 * j + g) * MM];
      half8 ha = *(const half8*)&ap[mb + alsw];
      half8 hb = *(const half8*)&ap[mb + 8 - alsw];
      zz[2 + j] = colstep(ha, hb, 64 * w + 32 + 8 * j + g, zz[2 + j]);
    }
    zz[6] = colstep(__builtin_bit_cast(half8, sa0),
                    __builtin_bit_cast(half8, sa1), 64 * w + g, zz[6]);
    zz[7] = colstep(__builtin_bit_cast(half8, sb0),
                    __builtin_bit_cast(half8, sb1), 64 * w + 8 + g, zz[7]);

    if (!last) {
      // ---- cross-group: xor8 (DPP row_ror:8) + xor32 (shfl); xor16 skipped
      // (g==0 and g==2 hold complementary partials -> 32 rows)
#pragma unroll
      for (int k = 0; k < 16; ++k) {
        t[k] = dpp_add<0x128>(t[k]);
        t[k] += __shfl_xor(t[k], 32);
      }
      if ((g & 5) == 0) {
        int row = 2 * w + (g >> 1);
#pragma unroll
        for (int s2 = 0; s2 < 4; ++s2) {
          f32x4 tv = {t[4 * s2], t[4 * s2 + 1], t[4 * s2 + 2], t[4 * s2 + 3]};
          *(f32x4*)&t_redW[row][mb + 4 * s2] = tv;
        }
      }
      __syncthreads();
      if (tid < MM) {
        float ssum = -b_sh[tid];
#pragma unroll
        for (int h = 0; h < 32; ++h) ssum += t_redW[h][tid];
        s_h[tid] = (_Float16)ssum;   // s = A*y - b for next pass's u
      }
      __syncthreads();
    }
  }
}

// ---------------------------------------------------------------------------
extern "C" void kernel_launch(void* const* d_in, const int* in_sizes, int n_in,
                              void* d_out, int out_size, void* d_ws, size_t ws_size,
                              hipStream_t stream) {
  const float* A  = (const float*)d_in[0];  // (BS, M, N)
  const float* bv = (const float*)d_in[1];  // (BS, M)
  const float* D1 = (const float*)d_in[2];  // (BS, N)
  const float* D2 = (const float*)d_in[3];  // (BS, N)
  float* out = (float*)d_out;               // (BS, N)

  _Float16* ATh = (_Float16*)d_ws;                              // 67 MB
  float* G = (float*)((char*)d_ws + (size_t)BS * NN * MM * 2);  // 16.7 MB
  // (fp16 Gh aliases each batch's own G slot after k_inv consumes it)

  k_aat<<<BS * 2, 512, 0, stream>>>(A, G, ATh);
  k_inv<<<BS, 1024, 0, stream>>>(G);
  k_main<<<BS, 1024, 0, stream>>>(ATh, G, bv, D1, D2, out);
}

// Round 8
// 730.188 us; speedup vs baseline: 1.2782x; 1.2782x over previous
//
#include <hip/hip_runtime.h>
#include <math.h>

#define BS 256
#define MM 128
#define NN 1024
#define ITERS 100
#define ALPHA 0.1f
#define AST 129
#define IST 129
#define TRP 132

typedef _Float16 half8 __attribute__((ext_vector_type(8)));
typedef _Float16 half4 __attribute__((ext_vector_type(4)));
typedef _Float16 half2v __attribute__((ext_vector_type(2)));
typedef float f32x4 __attribute__((ext_vector_type(4)));

// Exact butterfly add via DPP (VALU pipe, no LDS). Controls:
//   0xB1 quad_perm xor1 | 0x4E quad_perm xor2 | 0x141 row_half_mirror (xor7
//   within 8) | 0x128 row_ror:8 (xor8 within 16-lane row)
template <int CTRL>
__device__ __forceinline__ float dpp_add(float x) {
  int xi = __builtin_bit_cast(int, x);
  int r = __builtin_amdgcn_update_dpp(xi, xi, CTRL, 0xf, 0xf, true);
  return x + __builtin_bit_cast(float, r);
}

// ---------------------------------------------------------------------------
// AAT: 2 blocks per batch (row-halves p=0/1), 512 threads, 2 blocks/CU.
// Split-fp16 MFMA (hi/lo -> fp32-equivalent accuracy). Register prefetch of
// the next k-tile. Emits fp16 AT slices (conversion path unchanged).
__global__ __attribute__((amdgpu_waves_per_eu(4, 4)))
__launch_bounds__(512) void k_aat(const float* __restrict__ A,
                                  float* __restrict__ G,
                                  _Float16* __restrict__ ATh) {
  __shared__ float As[64 * AST];                          // 33,024
  __shared__ __align__(16) _Float16 Thi[8][2][64][8];     // 16,384
  __shared__ __align__(16) _Float16 Tlo[8][2][64][8];     // 16,384
  int b = blockIdx.x >> 1;
  int p = blockIdx.x & 1;          // row-half
  int tid = threadIdx.x;
  const float* Ab = A + (size_t)b * MM * NN;
  float* Cb = G + (size_t)b * MM * MM;
  _Float16* ATb = ATh + (size_t)b * NN * MM;

  int lane = tid & 63;
  int w = tid >> 6;      // wave 0..7
  int wr = w & 1;        // row strips {4p+2wr, 4p+2wr+1}
  int wc = w >> 1;       // col strips {2wc, 2wc+1}

  f32x4 acc[2][2];
#pragma unroll
  for (int i = 0; i < 2; ++i)
#pragma unroll
    for (int jj = 0; jj < 2; ++jj) acc[i][jj] = (f32x4){0.f, 0.f, 0.f, 0.f};

  float4 va[4];
#pragma unroll
  for (int s = 0; s < 4; ++s) {
    int c = tid + s * 512;
    int m = c >> 4;
    int kl = (c & 15) * 4;
    va[s] = *(const float4*)&Ab[(size_t)m * NN + kl];
  }

  for (int t = 0; t < 16; ++t) {
    int k0 = t * 64;
#pragma unroll
    for (int s = 0; s < 4; ++s) {
      int c = tid + s * 512;
      int m = c >> 4;
      int kl = (c & 15) * 4;
      float4 v = va[s];
      As[(kl + 0) * AST + m] = v.x;
      As[(kl + 1) * AST + m] = v.y;
      As[(kl + 2) * AST + m] = v.z;
      As[(kl + 3) * AST + m] = v.w;
      _Float16 h0 = (_Float16)v.x, h1 = (_Float16)v.y;
      _Float16 h2 = (_Float16)v.z, h3 = (_Float16)v.w;
      half4 hv = {h0, h1, h2, h3};
      half4 lv = {(_Float16)(v.x - (float)h0), (_Float16)(v.y - (float)h1),
                  (_Float16)(v.z - (float)h2), (_Float16)(v.w - (float)h3)};
      int strip = m >> 4;
      int kc = kl >> 5;
      int ln = (m & 15) + (((kl & 31) >> 3) << 4);
      int j0 = kl & 7;
      *(half4*)&Thi[strip][kc][ln][j0] = hv;
      *(half4*)&Tlo[strip][kc][ln][j0] = lv;
    }
    __syncthreads();
    if (t < 15) {
#pragma unroll
      for (int s = 0; s < 4; ++s) {
        int c = tid + s * 512;
        int m = c >> 4;
        int kl = (c & 15) * 4;
        va[s] = *(const float4*)&Ab[(size_t)m * NN + k0 + 64 + kl];
      }
    }
    // emit this block's half of the fp16 AT k-slice
#pragma unroll
    for (int s = 0; s < 4; ++s) {
      int idx = tid + s * 512;        // 0..2047
      int nl = 32 * p + (idx >> 6);   // 32p..32p+31
      int mp = idx & 63;
      half2v hv;
      hv[0] = (_Float16)As[nl * AST + 2 * mp];
      hv[1] = (_Float16)As[nl * AST + 2 * mp + 1];
      *(half2v*)&ATb[(size_t)(k0 + nl) * MM + 2 * mp] = hv;
    }
#pragma unroll
    for (int kc = 0; kc < 2; ++kc) {
      half8 ahi[2], alo[2], bhi[2], blo[2];
#pragma unroll
      for (int i = 0; i < 2; ++i) {
        ahi[i] = *(const half8*)&Thi[4 * p + 2 * wr + i][kc][lane][0];
        alo[i] = *(const half8*)&Tlo[4 * p + 2 * wr + i][kc][lane][0];
        bhi[i] = *(const half8*)&Thi[2 * wc + i][kc][lane][0];
        blo[i] = *(const half8*)&Tlo[2 * wc + i][kc][lane][0];
      }
#pragma unroll
      for (int i = 0; i < 2; ++i)
#pragma unroll
        for (int jj = 0; jj < 2; ++jj) {
          acc[i][jj] = __builtin_amdgcn_mfma_f32_16x16x32_f16(
              ahi[i], bhi[jj], acc[i][jj], 0, 0, 0);
          acc[i][jj] = __builtin_amdgcn_mfma_f32_16x16x32_f16(
              ahi[i], blo[jj], acc[i][jj], 0, 0, 0);
          acc[i][jj] = __builtin_amdgcn_mfma_f32_16x16x32_f16(
              alo[i], bhi[jj], acc[i][jj], 0, 0, 0);
        }
    }
    __syncthreads();
  }
  int rbase = 4 * (lane >> 4), cbase = lane & 15;
#pragma unroll
  for (int i = 0; i < 2; ++i)
#pragma unroll
    for (int jj = 0; jj < 2; ++jj) {
      int r0 = (4 * p + 2 * wr + i) * 16 + rbase;
      int c0 = (2 * wc + jj) * 16 + cbase;
#pragma unroll
      for (int r_ = 0; r_ < 4; ++r_)
        Cb[(size_t)(r0 + r_) * MM + c0] = acc[i][jj][r_];
    }
}

// ---------------------------------------------------------------------------
// INV: register-resident Gauss-Jordan (proven). 1024 thr, 1 barrier/step.
// Exports fp16 Gh aliased onto its own (fully consumed) G slot.
__global__ __attribute__((amdgpu_waves_per_eu(4, 4)))
__launch_bounds__(1024) void k_inv(float* __restrict__ G) {
  __shared__ float Msh[MM * IST];
  __shared__ float fcol[2][MM];
  __shared__ float frow[2][MM];
  int b = blockIdx.x;
  int tid = threadIdx.x;
  float* Gb = G + (size_t)b * MM * MM;
#pragma unroll
  for (int s = 0; s < 4; ++s) {
    int idx = (tid + s * 1024) * 4;
    float4 v = *(const float4*)&Gb[idx];
    int i = idx >> 7, j = idx & 127;
    Msh[i * IST + j + 0] = v.x;
    Msh[i * IST + j + 1] = v.y;
    Msh[i * IST + j + 2] = v.z;
    Msh[i * IST + j + 3] = v.w;
  }
  __syncthreads();
  int j = tid & 127;
  int i0 = (tid >> 7) * 16;
  float m[16];
#pragma unroll
  for (int ii = 0; ii < 16; ++ii) m[ii] = Msh[(i0 + ii) * IST + j];
  if (tid < MM) {
    fcol[0][tid] = Msh[tid * IST];   // col 0
    frow[0][tid] = Msh[tid];         // row 0
  }
  __syncthreads();
  int cur = 0;
  for (int kb = 0; kb < 8; ++kb) {
#pragma unroll
    for (int kq = 0; kq < 16; ++kq) {
      int k = kb * 16 + kq;
      float p = 1.0f / fcol[cur][k];
      float mkj = frow[cur][j];
      float fik[16];
#pragma unroll
      for (int q = 0; q < 4; ++q) {
        f32x4 fv = *(const f32x4*)&fcol[cur][i0 + 4 * q];
        fik[4 * q + 0] = fv[0]; fik[4 * q + 1] = fv[1];
        fik[4 * q + 2] = fv[2]; fik[4 * q + 3] = fv[3];
      }
      float pmkj = p * mkj;
      bool pivslab = (i0 == kb * 16);
      if (j == k) {
#pragma unroll
        for (int ii = 0; ii < 16; ++ii) m[ii] = -p * fik[ii];
        if (pivslab) m[kq] = p;
      } else {
#pragma unroll
        for (int ii = 0; ii < 16; ++ii) m[ii] = fmaf(-fik[ii], pmkj, m[ii]);
        if (pivslab) m[kq] = pmkj;
      }
      int nxt = cur ^ 1;
      if (k < MM - 1) {
        if (j == k + 1) {
#pragma unroll
          for (int ii = 0; ii < 16; ++ii) fcol[nxt][i0 + ii] = m[ii];
        }
        if (i0 == ((k + 1) & ~15)) frow[nxt][j] = m[(kq + 1) & 15];
      }
      __syncthreads();
      cur = nxt;
    }
  }
  _Float16* Ghb = (_Float16*)Gb;
#pragma unroll
  for (int ii = 0; ii < 16; ++ii)
    Ghb[(size_t)(i0 + ii) * MM + j] = (_Float16)m[ii];
}

// ---------------------------------------------------------------------------
// MAIN: persistent solver -- EXACT round-5 body (proven 452 us, 52 VGPR).
// REGISTER ENVELOPE IS HARD: 1024-thr block => 64 VGPR launch ceiling;
// round-6's med3 variant nudged liveness past it and spilled (WRITE_SIZE
// 1MB -> 41MB). Branch-form soft-threshold stays.
__global__ __attribute__((amdgpu_waves_per_eu(4, 4)))
__launch_bounds__(1024) void k_main(
    const _Float16* __restrict__ AT, const float* __restrict__ G,
    const float* __restrict__ bvec, const float* __restrict__ D1,
    const float* __restrict__ D2, float* __restrict__ out) {
  __shared__ __align__(16) _Float16 AL[512 * MM];   // 131,072
  __shared__ float2 tdi_sh[NN];                     // 8,192
  __shared__ float b_sh[MM];
  __shared__ __align__(16) _Float16 s_h[MM];
  __shared__ __align__(16) _Float16 u_h[MM];
  __shared__ __align__(16) float t_redW[32][TRP];   // 16,896

  int b = blockIdx.x;
  int tid = threadIdx.x;
  const _Float16* ATb = AT + (size_t)b * NN * MM;
  const _Float16* Ghb = (const _Float16*)(G + (size_t)b * MM * MM);

  // ---- G fragment: 8 threads per row, 16 elems each, packed fp16 (8 VGPRs)
  int sub = tid & 7, rrow = tid >> 3;
  float ghf[8];
  {
    half8 g0 = *(const half8*)&Ghb[(size_t)rrow * MM + 16 * sub];
    half8 g1 = *(const half8*)&Ghb[(size_t)rrow * MM + 16 * sub + 8];
    f32x4 gA = __builtin_bit_cast(f32x4, g0);
    f32x4 gB = __builtin_bit_cast(f32x4, g1);
#pragma unroll
    for (int s = 0; s < 4; ++s) {
      ghf[s] = gA[s];
      ghf[4 + s] = gB[s];
    }
  }
#pragma unroll
  for (int s = 0; s < 8; ++s) asm volatile("" : "+v"(ghf[s]));
  {
    float d1 = D1[(size_t)b * NN + tid];
    float d2 = D2[(size_t)b * NN + tid];
    float2 td2;
    td2.x = ALPHA * fabsf(d1);
    td2.y = 1.0f / (1.0f + 2.0f * ALPHA * d2 * d2);
    tdi_sh[tid] = td2;
  }
  if (tid < MM) {
    float bb = bvec[(size_t)b * MM + tid];
    b_sh[tid] = bb;
    s_h[tid] = (_Float16)(-bb);   // s_0 = A*y_0 - b = -b
  }

  int l8 = tid & 7;            // lane in 8-group
  int g = (tid >> 3) & 7;      // group within wave (8 groups)
  int w = tid >> 6;            // wave 0..15
  int mb = 16 * l8;            // m-slice base (16 elems/lane)
  int alsw = (g & 1) * 8;      // AL parity swizzle

  // ---- LDS cols: AL col c holds n = 64*(c>>5)+32+(c&31); 16B parity swizzle
#pragma unroll
  for (int i = 0; i < 8; ++i) {
    int c = tid + 1024 * i;
    int col = c >> 4;
    int m8 = (c & 15) * 8;
    int n = 32 * (col >> 5) + 32 + col;
    int phys = m8 ^ ((col & 1) << 3);
    *(half8*)&AL[col * MM + phys] = *(const half8*)&ATb[(size_t)n * MM + m8];
  }

  // ---- register cols: n = 64w+16+g and 64w+24+g (16 VGPRs, pinned)
  float rcw[16];
  {
    int n0 = 64 * w + 16 + g, n1 = 64 * w + 24 + g;
    f32x4 v0 = *(const f32x4*)&ATb[(size_t)n0 * MM + mb];
    f32x4 v1 = *(const f32x4*)&ATb[(size_t)n0 * MM + mb + 8];
    f32x4 v2 = *(const f32x4*)&ATb[(size_t)n1 * MM + mb];
    f32x4 v3 = *(const f32x4*)&ATb[(size_t)n1 * MM + mb + 8];
    rcw[0] = v0[0]; rcw[1] = v0[1]; rcw[2] = v0[2]; rcw[3] = v0[3];
    rcw[4] = v1[0]; rcw[5] = v1[1]; rcw[6] = v1[2]; rcw[7] = v1[3];
    rcw[8] = v2[0]; rcw[9] = v2[1]; rcw[10] = v2[2]; rcw[11] = v2[3];
    rcw[12] = v3[0]; rcw[13] = v3[1]; rcw[14] = v3[2]; rcw[15] = v3[3];
  }
#pragma unroll
  for (int k = 0; k < 16; ++k) asm volatile("" : "+v"(rcw[k]));

  // ---- z state in registers: 8 cols/group, replicated across the 8 lanes
  float zz[8];
#pragma unroll
  for (int k = 0; k < 8; ++k) zz[k] = 0.0f;

  __syncthreads();

  for (int it = 0; it < ITERS; ++it) {
    bool last = (it == ITERS - 1);

    // ---- issue streamed-col loads early (n = 64w+g, 64w+8+g)
    f32x4 sa0 = *(const f32x4*)&ATb[(size_t)(64 * w + g) * MM + mb];
    f32x4 sa1 = *(const f32x4*)&ATb[(size_t)(64 * w + g) * MM + mb + 8];
    f32x4 sb0 = *(const f32x4*)&ATb[(size_t)(64 * w + 8 + g) * MM + mb];
    f32x4 sb1 = *(const f32x4*)&ATb[(size_t)(64 * w + 8 + g) * MM + mb + 8];

    // ---- u = G * s  (8 threads per row, packed fp16 dot; DPP 8-lane reduce)
    {
      int j0 = 16 * sub;
      half8 sA = *(const half8*)&s_h[j0];
      half8 sB = *(const half8*)&s_h[j0 + 8];
      float up = 0.0f;
      up = __builtin_amdgcn_fdot2(__builtin_bit_cast(half2v, ghf[0]),
                                  __builtin_shufflevector(sA, sA, 0, 1), up, false);
      up = __builtin_amdgcn_fdot2(__builtin_bit_cast(half2v, ghf[1]),
                                  __builtin_shufflevector(sA, sA, 2, 3), up, false);
      up = __builtin_amdgcn_fdot2(__builtin_bit_cast(half2v, ghf[2]),
                                  __builtin_shufflevector(sA, sA, 4, 5), up, false);
      up = __builtin_amdgcn_fdot2(__builtin_bit_cast(half2v, ghf[3]),
                                  __builtin_shufflevector(sA, sA, 6, 7), up, false);
      up = __builtin_amdgcn_fdot2(__builtin_bit_cast(half2v, ghf[4]),
                                  __builtin_shufflevector(sB, sB, 0, 1), up, false);
      up = __builtin_amdgcn_fdot2(__builtin_bit_cast(half2v, ghf[5]),
                                  __builtin_shufflevector(sB, sB, 2, 3), up, false);
      up = __builtin_amdgcn_fdot2(__builtin_bit_cast(half2v, ghf[6]),
                                  __builtin_shufflevector(sB, sB, 4, 5), up, false);
      up = __builtin_amdgcn_fdot2(__builtin_bit_cast(half2v, ghf[7]),
                                  __builtin_shufflevector(sB, sB, 6, 7), up, false);
      up = dpp_add<0xB1>(up);
      up = dpp_add<0x4E>(up);
      up = dpp_add<0x141>(up);
      if (sub == 0) u_h[rrow] = (_Float16)up;
    }
    __syncthreads();
    half8 uA = *(const half8*)&u_h[mb];
    half8 uB = *(const half8*)&u_h[mb + 8];
    half2v u0 = __builtin_shufflevector(uA, uA, 0, 1);
    half2v u1 = __builtin_shufflevector(uA, uA, 2, 3);
    half2v u2 = __builtin_shufflevector(uA, uA, 4, 5);
    half2v u3 = __builtin_shufflevector(uA, uA, 6, 7);
    half2v u4 = __builtin_shufflevector(uB, uB, 0, 1);
    half2v u5 = __builtin_shufflevector(uB, uB, 2, 3);
    half2v u6 = __builtin_shufflevector(uB, uB, 4, 5);
    half2v u7 = __builtin_shufflevector(uB, uB, 6, 7);

    float t[16];
#pragma unroll
    for (int k = 0; k < 16; ++k) t[k] = 0.0f;

    // z passed BY VALUE, new z returned (no address-taken state).
    auto colstep = [&](half8 ha, half8 hb, int n, float zv) -> float {
      float cp = 0.0f;
      cp = __builtin_amdgcn_fdot2(__builtin_shufflevector(ha, ha, 0, 1), u0, cp, false);
      cp = __builtin_amdgcn_fdot2(__builtin_shufflevector(ha, ha, 2, 3), u1, cp, false);
      cp = __builtin_amdgcn_fdot2(__builtin_shufflevector(ha, ha, 4, 5), u2, cp, false);
      cp = __builtin_amdgcn_fdot2(__builtin_shufflevector(ha, ha, 6, 7), u3, cp, false);
      cp = __builtin_amdgcn_fdot2(__builtin_shufflevector(hb, hb, 0, 1), u4, cp, false);
      cp = __builtin_amdgcn_fdot2(__builtin_shufflevector(hb, hb, 2, 3), u5, cp, false);
      cp = __builtin_amdgcn_fdot2(__builtin_shufflevector(hb, hb, 4, 5), u6, cp, false);
      cp = __builtin_amdgcn_fdot2(__builtin_shufflevector(hb, hb, 6, 7), u7, cp, false);
      cp = dpp_add<0xB1>(cp);    // xor1
      cp = dpp_add<0x4E>(cp);    // xor2
      cp = dpp_add<0x141>(cp);   // half_mirror: 8-sum in all 8 lanes
      float2 tdi = tdi_sh[n];
      float td = tdi.x, di = tdi.y;
      float xm = zv - td, xp = zv + td;
      float xh = xm > 0.0f ? xm * di : (xp < 0.0f ? xp * di : 0.0f);
      if (!last) {
        float z1 = xh - cp;                     // z_{i+1}
        float xm1 = z1 - td, xp1 = z1 + td;
        float xh1 = xm1 > 0.0f ? xm1 * di : (xp1 < 0.0f ? xp1 * di : 0.0f);
        float y = 2.0f * xh1 - z1;              // y_{i+1}
        f32x4 wa = __builtin_bit_cast(f32x4, ha);
        f32x4 wb = __builtin_bit_cast(f32x4, hb);
#pragma unroll
        for (int i2 = 0; i2 < 4; ++i2) {
          asm("v_fma_mix_f32 %0, %1, %2, %0 op_sel_hi:[1,0,0]"
              : "+v"(t[2 * i2]) : "v"(wa[i2]), "v"(y));
          asm("v_fma_mix_f32 %0, %1, %2, %0 op_sel:[1,0,0] op_sel_hi:[1,0,0]"
              : "+v"(t[2 * i2 + 1]) : "v"(wa[i2]), "v"(y));
          asm("v_fma_mix_f32 %0, %1, %2, %0 op_sel_hi:[1,0,0]"
              : "+v"(t[8 + 2 * i2]) : "v"(wb[i2]), "v"(y));
          asm("v_fma_mix_f32 %0, %1, %2, %0 op_sel:[1,0,0] op_sel_hi:[1,0,0]"
              : "+v"(t[8 + 2 * i2 + 1]) : "v"(wb[i2]), "v"(y));
        }
        return z1;
      } else {
        float y = 2.0f * xh - zv;               // y_99 from z_99
        if (l8 == 0) out[(size_t)b * NN + n] = y - cp;   // x_99 direct
        return zv;
      }
    };

    // register cols, then LDS cols, then streamed (loads have arrived)
    {
      f32x4 ra = {rcw[0], rcw[1], rcw[2], rcw[3]};
      f32x4 rb = {rcw[4], rcw[5], rcw[6], rcw[7]};
      zz[0] = colstep(__builtin_bit_cast(half8, ra),
                      __builtin_bit_cast(half8, rb), 64 * w + 16 + g, zz[0]);
      f32x4 rc_ = {rcw[8], rcw[9], rcw[10], rcw[11]};
      f32x4 rd_ = {rcw[12], rcw[13], rcw[14], rcw[15]};
      zz[1] = colstep(__builtin_bit_cast(half8, rc_),
                      __builtin_bit_cast(half8, rd_), 64 * w + 24 + g, zz[1]);
    }
#pragma unroll
    for (int j = 0; j < 4; ++j) {
      const _Float16* ap = &AL[(32 * w + 8 * j + g) * MM];
      half8 ha = *(const half8*)&ap[mb + alsw];
      half8 hb = *(const half8*)&ap[mb + 8 - alsw];
      zz[2 + j] = colstep(ha, hb, 64 * w + 32 + 8 * j + g, zz[2 + j]);
    }
    zz[6] = colstep(__builtin_bit_cast(half8, sa0),
                    __builtin_bit_cast(half8, sa1), 64 * w + g, zz[6]);
    zz[7] = colstep(__builtin_bit_cast(half8, sb0),
                    __builtin_bit_cast(half8, sb1), 64 * w + 8 + g, zz[7]);

    if (!last) {
      // ---- cross-group: xor8 (DPP row_ror:8) + xor32 (shfl); xor16 skipped
      // (g==0 and g==2 hold complementary partials -> 32 rows)
#pragma unroll
      for (int k = 0; k < 16; ++k) {
        t[k] = dpp_add<0x128>(t[k]);
        t[k] += __shfl_xor(t[k], 32);
      }
      if ((g & 5) == 0) {
        int row = 2 * w + (g >> 1);
#pragma unroll
        for (int s2 = 0; s2 < 4; ++s2) {
          f32x4 tv = {t[4 * s2], t[4 * s2 + 1], t[4 * s2 + 2], t[4 * s2 + 3]};
          *(f32x4*)&t_redW[row][mb + 4 * s2] = tv;
        }
      }
      __syncthreads();
      if (tid < MM) {
        float ssum = -b_sh[tid];
#pragma unroll
        for (int h = 0; h < 32; ++h) ssum += t_redW[h][tid];
        s_h[tid] = (_Float16)ssum;   // s = A*y - b for next pass's u
      }
      __syncthreads();
    }
  }
}

// ---------------------------------------------------------------------------
extern "C" void kernel_launch(void* const* d_in, const int* in_sizes, int n_in,
                              void* d_out, int out_size, void* d_ws, size_t ws_size,
                              hipStream_t stream) {
  const float* A  = (const float*)d_in[0];  // (BS, M, N)
  const float* bv = (const float*)d_in[1];  // (BS, M)
  const float* D1 = (const float*)d_in[2];  // (BS, N)
  const float* D2 = (const float*)d_in[3];  // (BS, N)
  float* out = (float*)d_out;               // (BS, N)

  _Float16* ATh = (_Float16*)d_ws;                              // 67 MB
  float* G = (float*)((char*)d_ws + (size_t)BS * NN * MM * 2);  // 16.7 MB
  // (fp16 Gh aliases each batch's own G slot after k_inv consumes it)

  k_aat<<<BS * 2, 512, 0, stream>>>(A, G, ATh);
  k_inv<<<BS, 1024, 0, stream>>>(G);
  k_main<<<BS, 1024, 0, stream>>>(ATh, G, bv, D1, D2, out);
}